// Round 3
// baseline (1128.799 us; speedup 1.0000x reference)
//
#include <hip/hip_runtime.h>
#include <hip/hip_bf16.h>
#include <math.h>

// ---------------------------------------------------------------------------
// NasAutoGraphC round 3 (= round 2 resubmit; bench never ran due to GPU
// acquisition timeout).
//   * GEMMs: no LDS, no barriers. W (K x 128, <=256KB) streams from L1/L2
//     (same-address lanes merge); A rows read direct. 2x8 register tile
//     (4x8 for the K=512 pre-GEMM). 1250 blocks -> ~5 blocks/CU, lb(256,4).
//   * cheb + sage fused into ONE triple-A GEMM with dual accumulators and
//     leaky-combine epilogue (saves one 20.5MB round trip + launch per cell).
//   * graph preprocessing / CSR build / aggregation / classifier unchanged.
// ---------------------------------------------------------------------------

__device__ __forceinline__ float leaky01(float v) {
    return v > 0.f ? v : 0.01f * v;
}

__device__ __forceinline__ float f4c(const float4& v, int j) {
    return j == 0 ? v.x : j == 1 ? v.y : j == 2 ? v.z : v.w;
}

// ---- graph preprocessing ---------------------------------------------------

__global__ void init_nodes(float* __restrict__ deg, int* __restrict__ cnt,
                           float* __restrict__ loop_w, int n) {
    int i = blockIdx.x * blockDim.x + threadIdx.x;
    if (i < n) { deg[i] = 0.f; cnt[i] = 0; loop_w[i] = 1.0f; }
}

__global__ void edge_pass1(const int* __restrict__ src, const int* __restrict__ dst,
                           const float* __restrict__ ew, float* __restrict__ deg,
                           int* __restrict__ cnt, float* __restrict__ loop_w, int E) {
    int e = blockIdx.x * blockDim.x + threadIdx.x;
    if (e >= E) return;
    int s = src[e], d = dst[e];
    float w = ew[e];
    if (s == d) {
        loop_w[s] = w;                      // PyG keeps existing loop weight
    } else {
        atomicAdd(&deg[s], w);              // weighted out-degree (loops removed)
        atomicAdd(&cnt[d], 1);              // non-loop in-degree
    }
}

// single-block hierarchical exclusive scan over cnt -> offsets/cursor; also dis
__global__ void scan_kernel(const int* __restrict__ cnt, const float* __restrict__ deg,
                            int* __restrict__ offsets, int* __restrict__ cursor,
                            float* __restrict__ dis, int n) {
    __shared__ int wsum[16];
    __shared__ int carry;
    const int tid  = threadIdx.x;
    const int lane = tid & 63;
    const int wv   = tid >> 6;
    if (tid == 0) carry = 0;
    __syncthreads();
    const int nchunks = (n + 1023) >> 10;
    for (int ch = 0; ch < nchunks; ++ch) {
        int i = (ch << 10) + tid;
        int v = (i < n) ? cnt[i] : 0;
        if (i < n) {
            float d = deg[i];
            dis[i] = (d > 0.f) ? (1.0f / sqrtf(d)) : 0.f;
        }
        int incl = v;
        #pragma unroll
        for (int off = 1; off < 64; off <<= 1) {
            int t = __shfl_up(incl, off);
            if (lane >= off) incl += t;
        }
        if (lane == 63) wsum[wv] = incl;
        __syncthreads();
        if (tid < 16) {
            int s = wsum[tid];
            #pragma unroll
            for (int off = 1; off < 16; off <<= 1) {
                int u = __shfl_up(s, off);
                if (tid >= off) s += u;
            }
            wsum[tid] = s;                  // inclusive over wave totals
        }
        __syncthreads();
        int base = carry + (wv ? wsum[wv - 1] : 0);
        int excl = base + incl - v;
        if (i < n) { offsets[i] = excl; cursor[i] = excl; }
        __syncthreads();
        if (tid == 0) carry += wsum[15];
        __syncthreads();
    }
    if (tid == 0) offsets[n] = carry;
}

__global__ void edge_pass2(const int* __restrict__ src, const int* __restrict__ dst,
                           const float* __restrict__ ew, const float* __restrict__ dis,
                           int* __restrict__ cursor, int* __restrict__ slot_src,
                           float* __restrict__ slot_norm, float* __restrict__ slot_we,
                           int E) {
    int e = blockIdx.x * blockDim.x + threadIdx.x;
    if (e >= E) return;
    int s = src[e], d = dst[e];
    if (s == d) return;                     // loops contribute 0 to both aggs
    float w = ew[e];
    float nrm = -dis[s] * w * dis[d];
    int pos = atomicAdd(&cursor[d], 1);
    slot_src[pos]  = s;
    slot_norm[pos] = nrm;
    slot_we[pos]   = w;
}

// ---- aggregation: one wave per dst node; produces tx1 and sage-mean --------

__global__ __launch_bounds__(256) void aggregate_kernel(
    const float* __restrict__ xh, const int* __restrict__ offsets,
    const int* __restrict__ slot_src, const float* __restrict__ slot_norm,
    const float* __restrict__ slot_we, const float* __restrict__ loop_w,
    const int* __restrict__ cnt, float* __restrict__ tx1,
    float* __restrict__ sagg, int n)
{
    const int lane = threadIdx.x & 63;
    const int wv   = threadIdx.x >> 6;
    const int node = (blockIdx.x << 2) + wv;
    if (node >= n) return;
    const int beg = offsets[node], end = offsets[node + 1];
    const int c = lane << 1;                // 2 floats per lane = 128 dims
    float ax = 0.f, ay = 0.f, sx = 0.f, sy = 0.f;
    for (int e = beg; e < end; ++e) {
        const int   s  = slot_src[e];
        const float nr = slot_norm[e];
        const float we = slot_we[e];
        const float2 v = *(const float2*)&xh[((size_t)s << 7) + c];
        ax = fmaf(nr, v.x, ax); ay = fmaf(nr, v.y, ay);
        sx = fmaf(we, v.x, sx); sy = fmaf(we, v.y, sy);
    }
    const float2 vs = *(const float2*)&xh[((size_t)node << 7) + c];
    const float lw = loop_w[node];
    sx = fmaf(lw, vs.x, sx); sy = fmaf(lw, vs.y, sy);
    const float inv = 1.0f / (float)(cnt[node] + 1);
    *(float2*)&tx1[((size_t)node << 7) + c]  = make_float2(ax, ay);
    *(float2*)&sagg[((size_t)node << 7) + c] = make_float2(sx * inv, sy * inv);
}

// ---- barrier-free global-stream GEMM, N fixed at 128 -----------------------
// MODE 0: out = A1@W1 (+ A2@W2 if A2) + b1
// MODE 1: out = leaky(A1@W1 + A2@W2 + b1) + leaky(A3@W3 + b2)
// Thread tile: RPT rows x 8 cols. tx = tid&15 (col group), ty = tid>>4.
// A rows: 16 same-address lanes merge into one request. W rows: L1/L2-hot.

template<int RPT, int MODE>
__global__ __launch_bounds__(256, 4) void gemm_global(
    const float* __restrict__ A1, const float* __restrict__ W1, int K1,
    const float* __restrict__ A2, const float* __restrict__ W2, int K2,
    const float* __restrict__ A3, const float* __restrict__ W3, int K3,
    const float* __restrict__ b1, const float* __restrict__ b2,
    float* __restrict__ out, int M)
{
    const int tid  = threadIdx.x;
    const int tx   = tid & 15;
    const int ty   = tid >> 4;
    const int col0 = tx << 3;
    const int row0 = blockIdx.x * (RPT << 4) + ty * RPT;

    float accA[RPT][8];
    float accB[RPT][8];                     // dead (DCE'd) when MODE==0
    #pragma unroll
    for (int i = 0; i < RPT; ++i)
        #pragma unroll
        for (int j = 0; j < 8; ++j) { accA[i][j] = 0.f; accB[i][j] = 0.f; }

    const int nparts = MODE ? 3 : 2;
    #pragma unroll
    for (int part = 0; part < nparts; ++part) {
        const float* A = part == 0 ? A1 : part == 1 ? A2 : A3;
        const float* W = part == 0 ? W1 : part == 1 ? W2 : W3;
        const int    K = part == 0 ? K1 : part == 1 ? K2 : K3;
        if (A == nullptr) continue;
        const float* ap[RPT];
        #pragma unroll
        for (int i = 0; i < RPT; ++i) {
            int r = row0 + i; if (r > M - 1) r = M - 1;
            ap[i] = A + (size_t)r * K;
        }
        const float* wp = W + col0;
        for (int k = 0; k < K; k += 4) {
            float4 a[RPT];
            #pragma unroll
            for (int i = 0; i < RPT; ++i)
                a[i] = *(const float4*)(ap[i] + k);
            float4 wr0[4], wr1[4];
            #pragma unroll
            for (int j = 0; j < 4; ++j) {
                wr0[j] = *(const float4*)(wp + (size_t)(k + j) * 128);
                wr1[j] = *(const float4*)(wp + (size_t)(k + j) * 128 + 4);
            }
            #pragma unroll
            for (int j = 0; j < 4; ++j) {
                const float4 w0 = wr0[j], w1 = wr1[j];
                #pragma unroll
                for (int i = 0; i < RPT; ++i) {
                    const float av = f4c(a[i], j);
                    float* ac = (MODE == 1 && part == 2) ? accB[i] : accA[i];
                    ac[0] = fmaf(av, w0.x, ac[0]);
                    ac[1] = fmaf(av, w0.y, ac[1]);
                    ac[2] = fmaf(av, w0.z, ac[2]);
                    ac[3] = fmaf(av, w0.w, ac[3]);
                    ac[4] = fmaf(av, w1.x, ac[4]);
                    ac[5] = fmaf(av, w1.y, ac[5]);
                    ac[6] = fmaf(av, w1.z, ac[6]);
                    ac[7] = fmaf(av, w1.w, ac[7]);
                }
            }
        }
    }

    float bv1[8], bv2[8];
    #pragma unroll
    for (int j = 0; j < 8; ++j) {
        bv1[j] = b1[col0 + j];
        bv2[j] = MODE == 1 ? b2[col0 + j] : 0.f;
    }
    #pragma unroll
    for (int i = 0; i < RPT; ++i) {
        const int row = row0 + i;
        if (row >= M) continue;
        float v[8];
        #pragma unroll
        for (int j = 0; j < 8; ++j) v[j] = accA[i][j] + bv1[j];
        if (MODE == 1) {
            #pragma unroll
            for (int j = 0; j < 8; ++j)
                v[j] = leaky01(v[j]) + leaky01(accB[i][j] + bv2[j]);
        }
        float* op = &out[(size_t)row * 128 + col0];
        *(float4*)op       = make_float4(v[0], v[1], v[2], v[3]);
        *((float4*)op + 1) = make_float4(v[4], v[5], v[6], v[7]);
    }
}

// ---- classifier + log_softmax, wave per node -------------------------------

__global__ __launch_bounds__(256) void cls_kernel(
    const float* __restrict__ x2, const float* __restrict__ w,
    const float* __restrict__ b, float* __restrict__ out, int n, int C)
{
    const int lane = threadIdx.x & 63;
    const int wv   = threadIdx.x >> 6;
    const int node = (blockIdx.x << 2) + wv;
    if (node >= n) return;
    const float* xr = &x2[(size_t)node << 7];
    float acc;
    if (lane < C) {
        float a = 0.f;
        #pragma unroll 8
        for (int k = 0; k < 128; ++k) a = fmaf(xr[k], w[k * C + lane], a);
        acc = a + b[lane];
    } else {
        acc = -INFINITY;
    }
    float m = acc;
    #pragma unroll
    for (int off = 32; off; off >>= 1) m = fmaxf(m, __shfl_xor(m, off));
    float ex = (lane < C) ? expf(acc - m) : 0.f;
    float s = ex;
    #pragma unroll
    for (int off = 32; off; off >>= 1) s += __shfl_xor(s, off);
    const float ls = logf(s);
    if (lane < C) out[(size_t)node * C + lane] = acc - m - ls;
}

// ---------------------------------------------------------------------------

extern "C" void kernel_launch(void* const* d_in, const int* in_sizes, int n_in,
                              void* d_out, int out_size, void* d_ws, size_t ws_size,
                              hipStream_t stream)
{
    const float* x        = (const float*)d_in[0];
    const int*   ei       = (const int*)d_in[1];
    const float* ew       = (const float*)d_in[2];
    const float* pre_w1   = (const float*)d_in[3];
    const float* pre_b1   = (const float*)d_in[4];
    const float* cheb_w01 = (const float*)d_in[5];
    const float* cheb_w11 = (const float*)d_in[6];
    const float* cheb_b1  = (const float*)d_in[7];
    const float* sage_w1  = (const float*)d_in[8];
    const float* sage_b1  = (const float*)d_in[9];
    const float* lin_w1   = (const float*)d_in[10];
    const float* lin_b1   = (const float*)d_in[11];
    const float* pre_w2   = (const float*)d_in[12];
    const float* pre_b2   = (const float*)d_in[13];
    const float* cheb_w02 = (const float*)d_in[14];
    const float* cheb_w12 = (const float*)d_in[15];
    const float* cheb_b2  = (const float*)d_in[16];
    const float* sage_w2  = (const float*)d_in[17];
    const float* sage_b2  = (const float*)d_in[18];
    const float* lin_w2   = (const float*)d_in[19];
    const float* lin_b2   = (const float*)d_in[20];
    const float* cls_w    = (const float*)d_in[21];
    const float* cls_b    = (const float*)d_in[22];

    const int H    = 128;
    const int F_IN = in_sizes[3] / H;       // 512
    const int N    = in_sizes[0] / F_IN;    // 40000
    const int E    = in_sizes[2];           // 640000
    const int C    = in_sizes[21] / H;      // 40
    const int* src = ei;
    const int* dst = ei + E;

    // workspace carve-up (256B aligned); total ~91 MB
    char* p = (char*)d_ws;
    auto alloc = [&](size_t bytes) -> void* {
        void* r = (void*)p;
        p += (bytes + 255) & ~(size_t)255;
        return r;
    };
    float* buf0 = (float*)alloc((size_t)N * 128 * 4);
    float* buf1 = (float*)alloc((size_t)N * 128 * 4);
    float* buf2 = (float*)alloc((size_t)N * 128 * 4);
    float* buf3 = (float*)alloc((size_t)N * 128 * 4);
    float* deg     = (float*)alloc((size_t)N * 4);
    float* dis     = (float*)alloc((size_t)N * 4);
    float* loop_w  = (float*)alloc((size_t)N * 4);
    int*   cnt     = (int*)alloc((size_t)N * 4);
    int*   offs    = (int*)alloc((size_t)(N + 1) * 4);
    int*   cursor  = (int*)alloc((size_t)N * 4);
    int*   slot_src  = (int*)alloc((size_t)E * 4);
    float* slot_nrm  = (float*)alloc((size_t)E * 4);
    float* slot_we   = (float*)alloc((size_t)E * 4);
    (void)ws_size; (void)n_in; (void)out_size;

    const int nb_n  = (N + 255) / 256;
    const int nb_e  = (E + 255) / 256;
    const int nb_w  = (N + 3) / 4;          // wave-per-node kernels
    const int nb_g2 = (N + 31) / 32;        // RPT=2 GEMM blocks (1250)
    const int nb_g4 = (N + 63) / 64;        // RPT=4 GEMM blocks (625)

    // graph preprocessing (shared by both cells)
    init_nodes<<<nb_n, 256, 0, stream>>>(deg, cnt, loop_w, N);
    edge_pass1<<<nb_e, 256, 0, stream>>>(src, dst, ew, deg, cnt, loop_w, E);
    scan_kernel<<<1, 1024, 0, stream>>>(cnt, deg, offs, cursor, dis, N);
    edge_pass2<<<nb_e, 256, 0, stream>>>(src, dst, ew, dis, cursor,
                                         slot_src, slot_nrm, slot_we, E);

    // ---- cell 1 ----
    // xh = x @ pre_w1 + pre_b1                       -> buf0
    gemm_global<4, 0><<<nb_g4, 256, 0, stream>>>(
        x, pre_w1, F_IN, nullptr, nullptr, 0, nullptr, nullptr, 0,
        pre_b1, nullptr, buf0, N);
    // tx1 -> buf1, sage-mean -> buf2
    aggregate_kernel<<<nb_w, 256, 0, stream>>>(buf0, offs, slot_src, slot_nrm,
                                               slot_we, loop_w, cnt, buf1, buf2, N);
    // t = leaky(xh@cw0 + tx1@cw1 + cb) + leaky(sagg@sw + sb)   -> buf3
    gemm_global<2, 1><<<nb_g2, 256, 0, stream>>>(
        buf0, cheb_w01, H, buf1, cheb_w11, H, buf2, sage_w1, H,
        cheb_b1, sage_b1, buf3, N);
    // x1 = t @ lw + lb                               -> buf2
    gemm_global<2, 0><<<nb_g2, 256, 0, stream>>>(
        buf3, lin_w1, H, nullptr, nullptr, 0, nullptr, nullptr, 0,
        lin_b1, nullptr, buf2, N);

    // ---- cell 2 (input = buf2) ----
    gemm_global<2, 0><<<nb_g2, 256, 0, stream>>>(
        buf2, pre_w2, H, nullptr, nullptr, 0, nullptr, nullptr, 0,
        pre_b2, nullptr, buf0, N);
    aggregate_kernel<<<nb_w, 256, 0, stream>>>(buf0, offs, slot_src, slot_nrm,
                                               slot_we, loop_w, cnt, buf1, buf3, N);
    gemm_global<2, 1><<<nb_g2, 256, 0, stream>>>(
        buf0, cheb_w02, H, buf1, cheb_w12, H, buf3, sage_w2, H,
        cheb_b2, sage_b2, buf2, N);
    gemm_global<2, 0><<<nb_g2, 256, 0, stream>>>(
        buf2, lin_w2, H, nullptr, nullptr, 0, nullptr, nullptr, 0,
        lin_b2, nullptr, buf0, N);

    // classifier + log_softmax -> d_out
    cls_kernel<<<nb_w, 256, 0, stream>>>(buf0, cls_w, cls_b, (float*)d_out, N, C);
}

// Round 4
// 837.056 us; speedup vs baseline: 1.3485x; 1.3485x over previous
//
#include <hip/hip_runtime.h>
#include <hip/hip_bf16.h>
#include <math.h>

// ---------------------------------------------------------------------------
// NasAutoGraphC round 4.
// Post-mortem r3: barrier-free global-W GEMM was L2-latency-bound (W 64KB
// doesn't fit 32KB L1): VALUBusy 20%, 193us/GEMM. Fix:
//   * gemm_ldsw: W staged in LDS in 64-k chunks (32KB), A streamed from
//     global (row read once per block, 16 same-addr lanes merge). RPT=4x8
//     register tile -> 256 VALU cyc per 80 LDS cyc per 4-k. lb(256,3).
//   * ALGEBRAIC MERGE: no nonlinearity after (o1+o2)@lin_w, so
//     Wm1 = lin_w1@pre_w2 (precomputed on device) merges lin1+pre2 into one
//     GEMM, and Wm2 = lin_w2@cls_w folds lin2 into the classifier.
//     GEMM dispatches 8 -> 4 (+cls).
//   * preprocessing / CSR / aggregation / cls structure unchanged.
// ---------------------------------------------------------------------------

__device__ __forceinline__ float leaky01(float v) {
    return v > 0.f ? v : 0.01f * v;
}

__device__ __forceinline__ float f4c(const float4& v, int j) {
    return j == 0 ? v.x : j == 1 ? v.y : j == 2 ? v.z : v.w;
}

// ---- graph preprocessing ---------------------------------------------------

__global__ void init_nodes(float* __restrict__ deg, int* __restrict__ cnt,
                           float* __restrict__ loop_w, int n) {
    int i = blockIdx.x * blockDim.x + threadIdx.x;
    if (i < n) { deg[i] = 0.f; cnt[i] = 0; loop_w[i] = 1.0f; }
}

__global__ void edge_pass1(const int* __restrict__ src, const int* __restrict__ dst,
                           const float* __restrict__ ew, float* __restrict__ deg,
                           int* __restrict__ cnt, float* __restrict__ loop_w, int E) {
    int e = blockIdx.x * blockDim.x + threadIdx.x;
    if (e >= E) return;
    int s = src[e], d = dst[e];
    float w = ew[e];
    if (s == d) {
        loop_w[s] = w;                      // PyG keeps existing loop weight
    } else {
        atomicAdd(&deg[s], w);              // weighted out-degree (loops removed)
        atomicAdd(&cnt[d], 1);              // non-loop in-degree
    }
}

// single-block hierarchical exclusive scan over cnt -> offsets/cursor; also dis
__global__ void scan_kernel(const int* __restrict__ cnt, const float* __restrict__ deg,
                            int* __restrict__ offsets, int* __restrict__ cursor,
                            float* __restrict__ dis, int n) {
    __shared__ int wsum[16];
    __shared__ int carry;
    const int tid  = threadIdx.x;
    const int lane = tid & 63;
    const int wv   = tid >> 6;
    if (tid == 0) carry = 0;
    __syncthreads();
    const int nchunks = (n + 1023) >> 10;
    for (int ch = 0; ch < nchunks; ++ch) {
        int i = (ch << 10) + tid;
        int v = (i < n) ? cnt[i] : 0;
        if (i < n) {
            float d = deg[i];
            dis[i] = (d > 0.f) ? (1.0f / sqrtf(d)) : 0.f;
        }
        int incl = v;
        #pragma unroll
        for (int off = 1; off < 64; off <<= 1) {
            int t = __shfl_up(incl, off);
            if (lane >= off) incl += t;
        }
        if (lane == 63) wsum[wv] = incl;
        __syncthreads();
        if (tid < 16) {
            int s = wsum[tid];
            #pragma unroll
            for (int off = 1; off < 16; off <<= 1) {
                int u = __shfl_up(s, off);
                if (tid >= off) s += u;
            }
            wsum[tid] = s;                  // inclusive over wave totals
        }
        __syncthreads();
        int base = carry + (wv ? wsum[wv - 1] : 0);
        int excl = base + incl - v;
        if (i < n) { offsets[i] = excl; cursor[i] = excl; }
        __syncthreads();
        if (tid == 0) carry += wsum[15];
        __syncthreads();
    }
    if (tid == 0) offsets[n] = carry;
}

__global__ void edge_pass2(const int* __restrict__ src, const int* __restrict__ dst,
                           const float* __restrict__ ew, const float* __restrict__ dis,
                           int* __restrict__ cursor, int* __restrict__ slot_src,
                           float* __restrict__ slot_norm, float* __restrict__ slot_we,
                           int E) {
    int e = blockIdx.x * blockDim.x + threadIdx.x;
    if (e >= E) return;
    int s = src[e], d = dst[e];
    if (s == d) return;                     // loops contribute 0 to both aggs
    float w = ew[e];
    float nrm = -dis[s] * w * dis[d];
    int pos = atomicAdd(&cursor[d], 1);
    slot_src[pos]  = s;
    slot_norm[pos] = nrm;
    slot_we[pos]   = w;
}

// ---- weight-merge kernels (run once per call, tiny) ------------------------
// Wm[r][j] = sum_q A[r][q] * B[q][j]; row r==KA additionally emits merged bias
// bm[j] = sum_q ba[q] * B[q][j] + bb[j].

__global__ void merge_weights(const float* __restrict__ A, const float* __restrict__ B,
                              const float* __restrict__ ba, const float* __restrict__ bb,
                              float* __restrict__ Wm, float* __restrict__ bm,
                              int KA, int NB) {
    int idx = blockIdx.x * blockDim.x + threadIdx.x;
    int total = (KA + 1) * NB;
    if (idx >= total) return;
    int r = idx / NB, j = idx - r * NB;
    const float* arow = (r < KA) ? &A[(size_t)r * KA] : ba;
    float acc = 0.f;
    for (int q = 0; q < KA; ++q)
        acc = fmaf(arow[q], B[(size_t)q * NB + j], acc);
    if (r < KA) Wm[(size_t)r * NB + j] = acc;
    else        bm[j] = acc + bb[j];
}

// ---- aggregation: one wave per dst node; produces tx1 and sage-mean --------

__global__ __launch_bounds__(256) void aggregate_kernel(
    const float* __restrict__ xh, const int* __restrict__ offsets,
    const int* __restrict__ slot_src, const float* __restrict__ slot_norm,
    const float* __restrict__ slot_we, const float* __restrict__ loop_w,
    const int* __restrict__ cnt, float* __restrict__ tx1,
    float* __restrict__ sagg, int n)
{
    const int lane = threadIdx.x & 63;
    const int wv   = threadIdx.x >> 6;
    const int node = (blockIdx.x << 2) + wv;
    if (node >= n) return;
    const int beg = offsets[node], end = offsets[node + 1];
    const int c = lane << 1;                // 2 floats per lane = 128 dims
    float ax = 0.f, ay = 0.f, sx = 0.f, sy = 0.f;
    for (int e = beg; e < end; ++e) {
        const int   s  = slot_src[e];
        const float nr = slot_norm[e];
        const float we = slot_we[e];
        const float2 v = *(const float2*)&xh[((size_t)s << 7) + c];
        ax = fmaf(nr, v.x, ax); ay = fmaf(nr, v.y, ay);
        sx = fmaf(we, v.x, sx); sy = fmaf(we, v.y, sy);
    }
    const float2 vs = *(const float2*)&xh[((size_t)node << 7) + c];
    const float lw = loop_w[node];
    sx = fmaf(lw, vs.x, sx); sy = fmaf(lw, vs.y, sy);
    const float inv = 1.0f / (float)(cnt[node] + 1);
    *(float2*)&tx1[((size_t)node << 7) + c]  = make_float2(ax, ay);
    *(float2*)&sagg[((size_t)node << 7) + c] = make_float2(sx * inv, sy * inv);
}

// ---- GEMM: W LDS-staged in 64-k chunks, A streamed. N fixed at 128. --------
// MODE 0: out = A1@W1 (+ A2@W2) + b1
// MODE 1: out = leaky(A1@W1 + A2@W2 + b1) + leaky(A3@W3 + b2)
// Block: 256 threads, 64 rows x 128 cols. Thread: 4 rows x 8 cols.
// Per 4-k per thread: 128 FMA (256 VALU cyc) vs 8 ds_read_b128 (~80 cyc).

template<int MODE>
__global__ __launch_bounds__(256, 3) void gemm_ldsw(
    const float* __restrict__ A1, const float* __restrict__ W1, int K1,
    const float* __restrict__ A2, const float* __restrict__ W2, int K2,
    const float* __restrict__ A3, const float* __restrict__ W3, int K3,
    const float* __restrict__ b1, const float* __restrict__ b2,
    float* __restrict__ out, int M)
{
    __shared__ float Ws[64 * 128];          // 32 KB: one 64-k chunk of W
    const int tid  = threadIdx.x;
    const int tx   = tid & 15;
    const int ty   = tid >> 4;
    const int col0 = tx << 3;
    const int row0 = blockIdx.x * 64 + ty * 4;

    float accA[4][8];
    float accB[4][8];                       // DCE'd when MODE==0
    #pragma unroll
    for (int i = 0; i < 4; ++i)
        #pragma unroll
        for (int j = 0; j < 8; ++j) { accA[i][j] = 0.f; accB[i][j] = 0.f; }

    const int nparts = MODE ? 3 : 2;
    #pragma unroll
    for (int part = 0; part < nparts; ++part) {
        const float* A = part == 0 ? A1 : part == 1 ? A2 : A3;
        const float* W = part == 0 ? W1 : part == 1 ? W2 : W3;
        const int    K = part == 0 ? K1 : part == 1 ? K2 : K3;
        if (A == nullptr) continue;
        const float* ap[4];
        #pragma unroll
        for (int i = 0; i < 4; ++i) {
            int r = row0 + i; if (r > M - 1) r = M - 1;
            ap[i] = A + (size_t)r * K;
        }
        for (int k0 = 0; k0 < K; k0 += 64) {
            __syncthreads();                // protect previous chunk's readers
            {   // stage 64x128 W chunk: 2048 float4, 8 per thread, coalesced
                const float4* wsrc = (const float4*)(W + (size_t)k0 * 128);
                #pragma unroll
                for (int q = 0; q < 8; ++q)
                    ((float4*)Ws)[(q << 8) + tid] = wsrc[(q << 8) + tid];
            }
            __syncthreads();
            #pragma unroll 2
            for (int kk = 0; kk < 64; kk += 4) {
                float4 a[4];
                #pragma unroll
                for (int i = 0; i < 4; ++i)
                    a[i] = *(const float4*)(ap[i] + k0 + kk);
                #pragma unroll
                for (int j = 0; j < 4; ++j) {
                    const float4 w0 = *(const float4*)&Ws[(kk + j) * 128 + col0];
                    const float4 w1 = *(const float4*)&Ws[(kk + j) * 128 + col0 + 4];
                    #pragma unroll
                    for (int i = 0; i < 4; ++i) {
                        const float av = f4c(a[i], j);
                        float* ac = (MODE == 1 && part == 2) ? accB[i] : accA[i];
                        ac[0] = fmaf(av, w0.x, ac[0]);
                        ac[1] = fmaf(av, w0.y, ac[1]);
                        ac[2] = fmaf(av, w0.z, ac[2]);
                        ac[3] = fmaf(av, w0.w, ac[3]);
                        ac[4] = fmaf(av, w1.x, ac[4]);
                        ac[5] = fmaf(av, w1.y, ac[5]);
                        ac[6] = fmaf(av, w1.z, ac[6]);
                        ac[7] = fmaf(av, w1.w, ac[7]);
                    }
                }
            }
        }
    }

    float bv1[8], bv2[8];
    #pragma unroll
    for (int j = 0; j < 8; ++j) {
        bv1[j] = b1[col0 + j];
        bv2[j] = MODE == 1 ? b2[col0 + j] : 0.f;
    }
    #pragma unroll
    for (int i = 0; i < 4; ++i) {
        const int row = row0 + i;
        if (row >= M) continue;
        float v[8];
        #pragma unroll
        for (int j = 0; j < 8; ++j) v[j] = accA[i][j] + bv1[j];
        if (MODE == 1) {
            #pragma unroll
            for (int j = 0; j < 8; ++j)
                v[j] = leaky01(v[j]) + leaky01(accB[i][j] + bv2[j]);
        }
        float* op = &out[(size_t)row * 128 + col0];
        *(float4*)op       = make_float4(v[0], v[1], v[2], v[3]);
        *((float4*)op + 1) = make_float4(v[4], v[5], v[6], v[7]);
    }
}

// ---- classifier (merged lin2+cls weights) + log_softmax, wave per node -----

__global__ __launch_bounds__(256) void cls_kernel(
    const float* __restrict__ x2, const float* __restrict__ w,
    const float* __restrict__ b, float* __restrict__ out, int n, int C)
{
    const int lane = threadIdx.x & 63;
    const int wv   = threadIdx.x >> 6;
    const int node = (blockIdx.x << 2) + wv;
    if (node >= n) return;
    const float* xr = &x2[(size_t)node << 7];
    float acc;
    if (lane < C) {
        float a = 0.f;
        #pragma unroll 8
        for (int k = 0; k < 128; ++k) a = fmaf(xr[k], w[k * C + lane], a);
        acc = a + b[lane];
    } else {
        acc = -INFINITY;
    }
    float m = acc;
    #pragma unroll
    for (int off = 32; off; off >>= 1) m = fmaxf(m, __shfl_xor(m, off));
    float ex = (lane < C) ? expf(acc - m) : 0.f;
    float s = ex;
    #pragma unroll
    for (int off = 32; off; off >>= 1) s += __shfl_xor(s, off);
    const float ls = logf(s);
    if (lane < C) out[(size_t)node * C + lane] = acc - m - ls;
}

// ---------------------------------------------------------------------------

extern "C" void kernel_launch(void* const* d_in, const int* in_sizes, int n_in,
                              void* d_out, int out_size, void* d_ws, size_t ws_size,
                              hipStream_t stream)
{
    const float* x        = (const float*)d_in[0];
    const int*   ei       = (const int*)d_in[1];
    const float* ew       = (const float*)d_in[2];
    const float* pre_w1   = (const float*)d_in[3];
    const float* pre_b1   = (const float*)d_in[4];
    const float* cheb_w01 = (const float*)d_in[5];
    const float* cheb_w11 = (const float*)d_in[6];
    const float* cheb_b1  = (const float*)d_in[7];
    const float* sage_w1  = (const float*)d_in[8];
    const float* sage_b1  = (const float*)d_in[9];
    const float* lin_w1   = (const float*)d_in[10];
    const float* lin_b1   = (const float*)d_in[11];
    const float* pre_w2   = (const float*)d_in[12];
    const float* pre_b2   = (const float*)d_in[13];
    const float* cheb_w02 = (const float*)d_in[14];
    const float* cheb_w12 = (const float*)d_in[15];
    const float* cheb_b2  = (const float*)d_in[16];
    const float* sage_w2  = (const float*)d_in[17];
    const float* sage_b2  = (const float*)d_in[18];
    const float* lin_w2   = (const float*)d_in[19];
    const float* lin_b2   = (const float*)d_in[20];
    const float* cls_w    = (const float*)d_in[21];
    const float* cls_b    = (const float*)d_in[22];

    const int H    = 128;
    const int F_IN = in_sizes[3] / H;       // 512
    const int N    = in_sizes[0] / F_IN;    // 40000
    const int E    = in_sizes[2];           // 640000
    const int C    = in_sizes[21] / H;      // 40
    const int* src = ei;
    const int* dst = ei + E;

    // workspace carve-up (256B aligned)
    char* p = (char*)d_ws;
    auto alloc = [&](size_t bytes) -> void* {
        void* r = (void*)p;
        p += (bytes + 255) & ~(size_t)255;
        return r;
    };
    float* buf0 = (float*)alloc((size_t)N * 128 * 4);
    float* buf1 = (float*)alloc((size_t)N * 128 * 4);
    float* buf2 = (float*)alloc((size_t)N * 128 * 4);
    float* buf3 = (float*)alloc((size_t)N * 128 * 4);
    float* deg     = (float*)alloc((size_t)N * 4);
    float* dis     = (float*)alloc((size_t)N * 4);
    float* loop_w  = (float*)alloc((size_t)N * 4);
    int*   cnt     = (int*)alloc((size_t)N * 4);
    int*   offs    = (int*)alloc((size_t)(N + 1) * 4);
    int*   cursor  = (int*)alloc((size_t)N * 4);
    int*   slot_src  = (int*)alloc((size_t)E * 4);
    float* slot_nrm  = (float*)alloc((size_t)E * 4);
    float* slot_we   = (float*)alloc((size_t)E * 4);
    float* Wm1 = (float*)alloc((size_t)H * H * 4);   // lin_w1 @ pre_w2
    float* bm1 = (float*)alloc((size_t)H * 4);
    float* Wm2 = (float*)alloc((size_t)H * C * 4);   // lin_w2 @ cls_w
    float* bm2 = (float*)alloc((size_t)C * 4);
    (void)ws_size; (void)n_in; (void)out_size;

    const int nb_n = (N + 255) / 256;
    const int nb_e = (E + 255) / 256;
    const int nb_w = (N + 3) / 4;           // wave-per-node kernels
    const int nb_g = (N + 63) / 64;         // GEMM blocks (625)

    // graph preprocessing (shared by both cells) + weight merges
    init_nodes<<<nb_n, 256, 0, stream>>>(deg, cnt, loop_w, N);
    edge_pass1<<<nb_e, 256, 0, stream>>>(src, dst, ew, deg, cnt, loop_w, E);
    scan_kernel<<<1, 1024, 0, stream>>>(cnt, deg, offs, cursor, dis, N);
    edge_pass2<<<nb_e, 256, 0, stream>>>(src, dst, ew, dis, cursor,
                                         slot_src, slot_nrm, slot_we, E);
    merge_weights<<<((H + 1) * H + 255) / 256, 256, 0, stream>>>(
        lin_w1, pre_w2, lin_b1, pre_b2, Wm1, bm1, H, H);
    merge_weights<<<((H + 1) * C + 255) / 256, 256, 0, stream>>>(
        lin_w2, cls_w, lin_b2, cls_b, Wm2, bm2, H, C);

    // ---- cell 1 ----
    // xh1 = x @ pre_w1 + pre_b1                      -> buf0
    gemm_ldsw<0><<<nb_g, 256, 0, stream>>>(
        x, pre_w1, F_IN, nullptr, nullptr, 0, nullptr, nullptr, 0,
        pre_b1, nullptr, buf0, N);
    // tx1 -> buf1, sage-mean -> buf2
    aggregate_kernel<<<nb_w, 256, 0, stream>>>(buf0, offs, slot_src, slot_nrm,
                                               slot_we, loop_w, cnt, buf1, buf2, N);
    // t1 = leaky(xh@cw0 + tx1@cw1 + cb) + leaky(sagg@sw + sb)  -> buf3
    gemm_ldsw<1><<<nb_g, 256, 0, stream>>>(
        buf0, cheb_w01, H, buf1, cheb_w11, H, buf2, sage_w1, H,
        cheb_b1, sage_b1, buf3, N);
    // xh2 = t1 @ (lin_w1@pre_w2) + merged bias       -> buf0   [lin1+pre2]
    gemm_ldsw<0><<<nb_g, 256, 0, stream>>>(
        buf3, Wm1, H, nullptr, nullptr, 0, nullptr, nullptr, 0,
        bm1, nullptr, buf0, N);

    // ---- cell 2 ----
    aggregate_kernel<<<nb_w, 256, 0, stream>>>(buf0, offs, slot_src, slot_nrm,
                                               slot_we, loop_w, cnt, buf1, buf2, N);
    gemm_ldsw<1><<<nb_g, 256, 0, stream>>>(
        buf0, cheb_w02, H, buf1, cheb_w12, H, buf2, sage_w2, H,
        cheb_b2, sage_b2, buf3, N);

    // classifier with merged lin2+cls weights + log_softmax -> d_out
    cls_kernel<<<nb_w, 256, 0, stream>>>(buf3, Wm2, bm2, (float*)d_out, N, C);
}

// Round 5
// 812.218 us; speedup vs baseline: 1.3898x; 1.0306x over previous
//
#include <hip/hip_runtime.h>
#include <hip/hip_bf16.h>
#include <math.h>

// ---------------------------------------------------------------------------
// NasAutoGraphC round 5: GEMMs on the matrix pipe via split-bf16 MFMA.
//   * activations stored packed: uint32 = (bf16_hi << 16) | bf16_lo; value =
//     hi + lo reconstructs fp32 to ~2^-17 rel err.
//   * product: hi*hi + hi*lo + lo*hi  (3x mfma_f32_16x16x32_bf16, fp32 acc).
//   * weights: merged (lin1@pre2, lin2@cls) then converted once per call to
//     packed + TRANSPOSED [col][K] so B-frags are contiguous 32B/lane loads.
//   * GEMM kernel: no LDS, no barriers. Wave tile 32x64, block 2Mx2N waves,
//     grid 625, A/B frags straight from global (weights L2-hot).
//   * aggregate/cls read+write packed. CSR preprocessing unchanged.
// MFMA layouts used (guide-verified C/D, standard A/B):
//   A: row=lane&15, k=(lane>>4)*8+i   B: col=lane&15, k=(lane>>4)*8+i
//   C/D: col=lane&15, row=(lane>>4)*4+reg   [learn_hip m89]
// ---------------------------------------------------------------------------

typedef __attribute__((ext_vector_type(8))) short bf16x8;
typedef __attribute__((ext_vector_type(4))) float f32x4;

__device__ __forceinline__ float leaky01(float v) {
    return v > 0.f ? v : 0.01f * v;
}

// ---- packed hi/lo bf16 helpers ---------------------------------------------

__device__ __forceinline__ uint32_t rne_bf16(float f) {
    uint32_t u = __float_as_uint(f);
    return (u + 0x7FFFu + ((u >> 16) & 1u)) >> 16;
}
__device__ __forceinline__ uint32_t pack_hilo(float v) {
    uint32_t h = rne_bf16(v);
    float hf = __uint_as_float(h << 16);
    uint32_t l = rne_bf16(v - hf);
    return (h << 16) | l;
}
__device__ __forceinline__ float unpack_hilo(uint32_t p) {
    return __uint_as_float(p & 0xFFFF0000u) + __uint_as_float(p << 16);
}

struct FragPair { bf16x8 hi, lo; };

// 8 packed elems (k-consecutive) -> hi frag + lo frag
__device__ __forceinline__ FragPair load_packed_frag(const uint32_t* p) {
    uint4 a = *(const uint4*)p;
    uint4 b = *(const uint4*)(p + 4);
    uint32_t q[8] = {a.x, a.y, a.z, a.w, b.x, b.y, b.z, b.w};
    union { uint32_t u[4]; bf16x8 v; } h, lo;
    #pragma unroll
    for (int i = 0; i < 4; ++i) {
        h.u[i]  = (q[2*i] >> 16)      | (q[2*i+1] & 0xFFFF0000u);
        lo.u[i] = (q[2*i] & 0xFFFFu)  | (q[2*i+1] << 16);
    }
    FragPair r; r.hi = h.v; r.lo = lo.v; return r;
}

// 8 fp32 elems -> hi/lo frags (for the raw x input)
__device__ __forceinline__ FragPair cvt_frag_f32(const float* p) {
    float4 a = *(const float4*)p;
    float4 b = *(const float4*)(p + 4);
    float f[8] = {a.x, a.y, a.z, a.w, b.x, b.y, b.z, b.w};
    uint32_t hb[8], lb[8];
    #pragma unroll
    for (int i = 0; i < 8; ++i) {
        hb[i] = rne_bf16(f[i]);
        lb[i] = rne_bf16(f[i] - __uint_as_float(hb[i] << 16));
    }
    union { uint32_t u[4]; bf16x8 v; } h, lo;
    #pragma unroll
    for (int i = 0; i < 4; ++i) {
        h.u[i]  = hb[2*i] | (hb[2*i+1] << 16);
        lo.u[i] = lb[2*i] | (lb[2*i+1] << 16);
    }
    FragPair r; r.hi = h.v; r.lo = lo.v; return r;
}

// ---- graph preprocessing ---------------------------------------------------

__global__ void init_nodes(float* __restrict__ deg, int* __restrict__ cnt,
                           float* __restrict__ loop_w, int n) {
    int i = blockIdx.x * blockDim.x + threadIdx.x;
    if (i < n) { deg[i] = 0.f; cnt[i] = 0; loop_w[i] = 1.0f; }
}

__global__ void edge_pass1(const int* __restrict__ src, const int* __restrict__ dst,
                           const float* __restrict__ ew, float* __restrict__ deg,
                           int* __restrict__ cnt, float* __restrict__ loop_w, int E) {
    int e = blockIdx.x * blockDim.x + threadIdx.x;
    if (e >= E) return;
    int s = src[e], d = dst[e];
    float w = ew[e];
    if (s == d) {
        loop_w[s] = w;                      // PyG keeps existing loop weight
    } else {
        atomicAdd(&deg[s], w);
        atomicAdd(&cnt[d], 1);
    }
}

__global__ void scan_kernel(const int* __restrict__ cnt, const float* __restrict__ deg,
                            int* __restrict__ offsets, int* __restrict__ cursor,
                            float* __restrict__ dis, int n) {
    __shared__ int wsum[16];
    __shared__ int carry;
    const int tid  = threadIdx.x;
    const int lane = tid & 63;
    const int wv   = tid >> 6;
    if (tid == 0) carry = 0;
    __syncthreads();
    const int nchunks = (n + 1023) >> 10;
    for (int ch = 0; ch < nchunks; ++ch) {
        int i = (ch << 10) + tid;
        int v = (i < n) ? cnt[i] : 0;
        if (i < n) {
            float d = deg[i];
            dis[i] = (d > 0.f) ? (1.0f / sqrtf(d)) : 0.f;
        }
        int incl = v;
        #pragma unroll
        for (int off = 1; off < 64; off <<= 1) {
            int t = __shfl_up(incl, off);
            if (lane >= off) incl += t;
        }
        if (lane == 63) wsum[wv] = incl;
        __syncthreads();
        if (tid < 16) {
            int s = wsum[tid];
            #pragma unroll
            for (int off = 1; off < 16; off <<= 1) {
                int u = __shfl_up(s, off);
                if (tid >= off) s += u;
            }
            wsum[tid] = s;
        }
        __syncthreads();
        int base = carry + (wv ? wsum[wv - 1] : 0);
        int excl = base + incl - v;
        if (i < n) { offsets[i] = excl; cursor[i] = excl; }
        __syncthreads();
        if (tid == 0) carry += wsum[15];
        __syncthreads();
    }
    if (tid == 0) offsets[n] = carry;
}

__global__ void edge_pass2(const int* __restrict__ src, const int* __restrict__ dst,
                           const float* __restrict__ ew, const float* __restrict__ dis,
                           int* __restrict__ cursor, int* __restrict__ slot_src,
                           float* __restrict__ slot_norm, float* __restrict__ slot_we,
                           int E) {
    int e = blockIdx.x * blockDim.x + threadIdx.x;
    if (e >= E) return;
    int s = src[e], d = dst[e];
    if (s == d) return;
    float w = ew[e];
    float nrm = -dis[s] * w * dis[d];
    int pos = atomicAdd(&cursor[d], 1);
    slot_src[pos]  = s;
    slot_norm[pos] = nrm;
    slot_we[pos]   = w;
}

// ---- weight merge (fp32, tiny) ---------------------------------------------

__global__ void merge_weights(const float* __restrict__ A, const float* __restrict__ B,
                              const float* __restrict__ ba, const float* __restrict__ bb,
                              float* __restrict__ Wm, float* __restrict__ bm,
                              int KA, int NB) {
    int idx = blockIdx.x * blockDim.x + threadIdx.x;
    int total = (KA + 1) * NB;
    if (idx >= total) return;
    int r = idx / NB, j = idx - r * NB;
    const float* arow = (r < KA) ? &A[(size_t)r * KA] : ba;
    float acc = 0.f;
    for (int q = 0; q < KA; ++q)
        acc = fmaf(arow[q], B[(size_t)q * NB + j], acc);
    if (r < KA) Wm[(size_t)r * NB + j] = acc;
    else        bm[j] = acc + bb[j];
}

// ---- weight convert: fp32 [K][128] -> packed TRANSPOSED [128][K] -----------
// 8 segments: pre_w1 (K=512) + 7x (K=128): cw01,cw11,sw1,Wm1,cw02,cw12,sw2.

__global__ void convert_weights(const float* s0, const float* s1, const float* s2,
                                const float* s3, const float* s4, const float* s5,
                                const float* s6, const float* s7,
                                uint32_t* __restrict__ dst) {
    int idx = blockIdx.x * blockDim.x + threadIdx.x;
    if (idx >= 65536 + 7 * 16384) return;
    const float* src; int K, local; uint32_t* d;
    if (idx < 65536) { src = s0; K = 512; local = idx; d = dst; }
    else {
        int t = idx - 65536;
        int seg = t >> 14; local = t & 16383; K = 128;
        d = dst + 65536 + (seg << 14);
        src = seg == 0 ? s1 : seg == 1 ? s2 : seg == 2 ? s3 :
              seg == 3 ? s4 : seg == 4 ? s5 : seg == 5 ? s6 : s7;
    }
    int col = local / K, k = local - col * K;
    d[local] = pack_hilo(src[(size_t)k * 128 + col]);
}

// ---- aggregation (packed IO): wave per node, tx1 + sage-mean ---------------

__global__ __launch_bounds__(256) void aggregate_packed(
    const uint32_t* __restrict__ xh, const int* __restrict__ offsets,
    const int* __restrict__ slot_src, const float* __restrict__ slot_norm,
    const float* __restrict__ slot_we, const float* __restrict__ loop_w,
    const int* __restrict__ cnt, uint32_t* __restrict__ tx1,
    uint32_t* __restrict__ sagg, int n)
{
    const int lane = threadIdx.x & 63;
    const int wv   = threadIdx.x >> 6;
    const int node = (blockIdx.x << 2) + wv;
    if (node >= n) return;
    const int beg = offsets[node], end = offsets[node + 1];
    const int c = lane << 1;
    float ax = 0.f, ay = 0.f, sx = 0.f, sy = 0.f;
    for (int e = beg; e < end; ++e) {
        const int   s  = slot_src[e];
        const float nr = slot_norm[e];
        const float we = slot_we[e];
        const uint2 p = *(const uint2*)&xh[((size_t)s << 7) + c];
        const float vx = unpack_hilo(p.x), vy = unpack_hilo(p.y);
        ax = fmaf(nr, vx, ax); ay = fmaf(nr, vy, ay);
        sx = fmaf(we, vx, sx); sy = fmaf(we, vy, sy);
    }
    const uint2 ps = *(const uint2*)&xh[((size_t)node << 7) + c];
    const float lw = loop_w[node];
    sx = fmaf(lw, unpack_hilo(ps.x), sx); sy = fmaf(lw, unpack_hilo(ps.y), sy);
    const float inv = 1.0f / (float)(cnt[node] + 1);
    uint2 o1 = make_uint2(pack_hilo(ax), pack_hilo(ay));
    uint2 o2 = make_uint2(pack_hilo(sx * inv), pack_hilo(sy * inv));
    *(uint2*)&tx1[((size_t)node << 7) + c]  = o1;
    *(uint2*)&sagg[((size_t)node << 7) + c] = o2;
}

// ---- split-bf16 MFMA GEMM (no LDS, no barriers) ----------------------------
// One k-loop over one (A, Wt) pair; accumulates into acc[2][4].

template<bool F32>
__device__ __forceinline__ void gemm_part(
    const void* Av, const uint32_t* __restrict__ Wt, int K,
    int rbase, int cbase, int l15, int kg, f32x4 acc[2][4])
{
    for (int k = 0; k < K; k += 32) {
        FragPair Af[2];
        #pragma unroll
        for (int m = 0; m < 2; ++m) {
            const int row = rbase + m * 16 + l15;
            if constexpr (F32)
                Af[m] = cvt_frag_f32((const float*)Av + (size_t)row * K + k + kg * 8);
            else
                Af[m] = load_packed_frag((const uint32_t*)Av + (size_t)row * K + k + kg * 8);
        }
        #pragma unroll
        for (int n = 0; n < 4; ++n) {
            const FragPair Bf =
                load_packed_frag(Wt + (size_t)(cbase + n * 16 + l15) * K + k + kg * 8);
            #pragma unroll
            for (int m = 0; m < 2; ++m) {
                acc[m][n] = __builtin_amdgcn_mfma_f32_16x16x32_bf16(Af[m].hi, Bf.hi, acc[m][n], 0, 0, 0);
                acc[m][n] = __builtin_amdgcn_mfma_f32_16x16x32_bf16(Af[m].hi, Bf.lo, acc[m][n], 0, 0, 0);
                acc[m][n] = __builtin_amdgcn_mfma_f32_16x16x32_bf16(Af[m].lo, Bf.hi, acc[m][n], 0, 0, 0);
            }
        }
    }
}

// NPARTS=1: out = A1@W1 + b1
// NPARTS=3: out = leaky(A1@W1 + A2@W2 + b1) + leaky(A3@W3 + b2)
// Block 256 = 4 waves (2M x 2N); wave tile 32 rows x 64 cols; BM=64, BN=128.
template<int NPARTS, bool AF32>
__global__ __launch_bounds__(256, 3) void gemm_mfma(
    const void* __restrict__ A1, const uint32_t* __restrict__ Wt1, int K1,
    const uint32_t* __restrict__ A2, const uint32_t* __restrict__ Wt2,
    const uint32_t* __restrict__ A3, const uint32_t* __restrict__ Wt3,
    const float* __restrict__ b1, const float* __restrict__ b2,
    uint32_t* __restrict__ out, int M)
{
    const int tid  = threadIdx.x;
    const int lane = tid & 63;
    const int w    = tid >> 6;
    const int mw   = w >> 1, nw = w & 1;
    const int l15  = lane & 15;
    const int kg   = lane >> 4;
    const int rbase = blockIdx.x * 64 + mw * 32;
    const int cbase = nw * 64;

    f32x4 accA[2][4];
    #pragma unroll
    for (int m = 0; m < 2; ++m)
        #pragma unroll
        for (int n = 0; n < 4; ++n) accA[m][n] = (f32x4)0.f;

    gemm_part<AF32>(A1, Wt1, K1, rbase, cbase, l15, kg, accA);

    if constexpr (NPARTS == 3) {
        gemm_part<false>(A2, Wt2, 128, rbase, cbase, l15, kg, accA);
        f32x4 accB[2][4];
        #pragma unroll
        for (int m = 0; m < 2; ++m)
            #pragma unroll
            for (int n = 0; n < 4; ++n) accB[m][n] = (f32x4)0.f;
        gemm_part<false>(A3, Wt3, 128, rbase, cbase, l15, kg, accB);

        #pragma unroll
        for (int n = 0; n < 4; ++n) {
            const int col = cbase + n * 16 + l15;
            const float bb1 = b1[col], bb2 = b2[col];
            #pragma unroll
            for (int m = 0; m < 2; ++m)
                #pragma unroll
                for (int r = 0; r < 4; ++r) {
                    const int row = rbase + m * 16 + kg * 4 + r;
                    float v = leaky01(accA[m][n][r] + bb1) + leaky01(accB[m][n][r] + bb2);
                    out[(size_t)row * 128 + col] = pack_hilo(v);
                }
        }
    } else {
        #pragma unroll
        for (int n = 0; n < 4; ++n) {
            const int col = cbase + n * 16 + l15;
            const float bb1 = b1[col];
            #pragma unroll
            for (int m = 0; m < 2; ++m)
                #pragma unroll
                for (int r = 0; r < 4; ++r) {
                    const int row = rbase + m * 16 + kg * 4 + r;
                    out[(size_t)row * 128 + col] = pack_hilo(accA[m][n][r] + bb1);
                }
        }
    }
    (void)M;
}

// ---- classifier (merged lin2+cls) + log_softmax, wave per node -------------

__global__ __launch_bounds__(256) void cls_kernel(
    const uint32_t* __restrict__ x2, const float* __restrict__ w,
    const float* __restrict__ b, float* __restrict__ out, int n, int C)
{
    const int lane = threadIdx.x & 63;
    const int wv   = threadIdx.x >> 6;
    const int node = (blockIdx.x << 2) + wv;
    if (node >= n) return;
    const uint32_t* xr = &x2[(size_t)node << 7];
    float acc;
    if (lane < C) {
        float a = 0.f;
        #pragma unroll 8
        for (int k = 0; k < 128; ++k)
            a = fmaf(unpack_hilo(xr[k]), w[k * C + lane], a);
        acc = a + b[lane];
    } else {
        acc = -INFINITY;
    }
    float m = acc;
    #pragma unroll
    for (int off = 32; off; off >>= 1) m = fmaxf(m, __shfl_xor(m, off));
    float ex = (lane < C) ? expf(acc - m) : 0.f;
    float s = ex;
    #pragma unroll
    for (int off = 32; off; off >>= 1) s += __shfl_xor(s, off);
    const float ls = logf(s);
    if (lane < C) out[(size_t)node * C + lane] = acc - m - ls;
}

// ---------------------------------------------------------------------------

extern "C" void kernel_launch(void* const* d_in, const int* in_sizes, int n_in,
                              void* d_out, int out_size, void* d_ws, size_t ws_size,
                              hipStream_t stream)
{
    const float* x        = (const float*)d_in[0];
    const int*   ei       = (const int*)d_in[1];
    const float* ew       = (const float*)d_in[2];
    const float* pre_w1   = (const float*)d_in[3];
    const float* pre_b1   = (const float*)d_in[4];
    const float* cheb_w01 = (const float*)d_in[5];
    const float* cheb_w11 = (const float*)d_in[6];
    const float* cheb_b1  = (const float*)d_in[7];
    const float* sage_w1  = (const float*)d_in[8];
    const float* sage_b1  = (const float*)d_in[9];
    const float* lin_w1   = (const float*)d_in[10];
    const float* lin_b1   = (const float*)d_in[11];
    const float* pre_w2   = (const float*)d_in[12];
    const float* pre_b2   = (const float*)d_in[13];
    const float* cheb_w02 = (const float*)d_in[14];
    const float* cheb_w12 = (const float*)d_in[15];
    const float* cheb_b2  = (const float*)d_in[16];
    const float* sage_w2  = (const float*)d_in[17];
    const float* sage_b2  = (const float*)d_in[18];
    const float* lin_w2   = (const float*)d_in[19];
    const float* lin_b2   = (const float*)d_in[20];
    const float* cls_w    = (const float*)d_in[21];
    const float* cls_b    = (const float*)d_in[22];

    const int H    = 128;
    const int F_IN = in_sizes[3] / H;       // 512
    const int N    = in_sizes[0] / F_IN;    // 40000
    const int E    = in_sizes[2];           // 640000
    const int C    = in_sizes[21] / H;      // 40
    const int* src = ei;
    const int* dst = ei + E;

    // workspace carve-up (256B aligned)
    char* p = (char*)d_ws;
    auto alloc = [&](size_t bytes) -> void* {
        void* r = (void*)p;
        p += (bytes + 255) & ~(size_t)255;
        return r;
    };
    uint32_t* buf0 = (uint32_t*)alloc((size_t)N * 128 * 4);   // packed activations
    uint32_t* buf1 = (uint32_t*)alloc((size_t)N * 128 * 4);
    uint32_t* buf2 = (uint32_t*)alloc((size_t)N * 128 * 4);
    uint32_t* buf3 = (uint32_t*)alloc((size_t)N * 128 * 4);
    float* deg     = (float*)alloc((size_t)N * 4);
    float* dis     = (float*)alloc((size_t)N * 4);
    float* loop_w  = (float*)alloc((size_t)N * 4);
    int*   cnt     = (int*)alloc((size_t)N * 4);
    int*   offs    = (int*)alloc((size_t)(N + 1) * 4);
    int*   cursor  = (int*)alloc((size_t)N * 4);
    int*   slot_src  = (int*)alloc((size_t)E * 4);
    float* slot_nrm  = (float*)alloc((size_t)E * 4);
    float* slot_we   = (float*)alloc((size_t)E * 4);
    float* Wm1 = (float*)alloc((size_t)H * H * 4);    // lin_w1 @ pre_w2 (fp32)
    float* bm1 = (float*)alloc((size_t)H * 4);
    float* Wm2 = (float*)alloc((size_t)H * C * 4);    // lin_w2 @ cls_w (fp32)
    float* bm2 = (float*)alloc((size_t)C * 4);
    uint32_t* wt = (uint32_t*)alloc((size_t)(65536 + 7 * 16384) * 4);  // packed W^T
    (void)ws_size; (void)n_in; (void)out_size;

    uint32_t* wt_pre  = wt;                 // [128][512]
    uint32_t* wt_cw01 = wt + 65536;
    uint32_t* wt_cw11 = wt_cw01 + 16384;
    uint32_t* wt_sw1  = wt_cw11 + 16384;
    uint32_t* wt_Wm1  = wt_sw1  + 16384;
    uint32_t* wt_cw02 = wt_Wm1  + 16384;
    uint32_t* wt_cw12 = wt_cw02 + 16384;
    uint32_t* wt_sw2  = wt_cw12 + 16384;

    const int nb_n = (N + 255) / 256;
    const int nb_e = (E + 255) / 256;
    const int nb_w = (N + 3) / 4;           // wave-per-node kernels
    const int nb_g = (N + 63) / 64;         // MFMA GEMM blocks (625)

    // graph preprocessing + weight merge/convert
    init_nodes<<<nb_n, 256, 0, stream>>>(deg, cnt, loop_w, N);
    edge_pass1<<<nb_e, 256, 0, stream>>>(src, dst, ew, deg, cnt, loop_w, E);
    scan_kernel<<<1, 1024, 0, stream>>>(cnt, deg, offs, cursor, dis, N);
    edge_pass2<<<nb_e, 256, 0, stream>>>(src, dst, ew, dis, cursor,
                                         slot_src, slot_nrm, slot_we, E);
    merge_weights<<<((H + 1) * H + 255) / 256, 256, 0, stream>>>(
        lin_w1, pre_w2, lin_b1, pre_b2, Wm1, bm1, H, H);
    merge_weights<<<((H + 1) * C + 255) / 256, 256, 0, stream>>>(
        lin_w2, cls_w, lin_b2, cls_b, Wm2, bm2, H, C);
    convert_weights<<<(65536 + 7 * 16384 + 255) / 256, 256, 0, stream>>>(
        pre_w1, cheb_w01, cheb_w11, sage_w1, Wm1, cheb_w02, cheb_w12, sage_w2, wt);

    // ---- cell 1 ----
    // xh1 = x @ pre_w1 + pre_b1                       -> buf0 (packed)
    gemm_mfma<1, true><<<nb_g, 256, 0, stream>>>(
        x, wt_pre, F_IN, nullptr, nullptr, nullptr, nullptr,
        pre_b1, nullptr, buf0, N);
    // tx1 -> buf1, sage-mean -> buf2
    aggregate_packed<<<nb_w, 256, 0, stream>>>(buf0, offs, slot_src, slot_nrm,
                                               slot_we, loop_w, cnt, buf1, buf2, N);
    // t1 = leaky(xh@cw0 + tx1@cw1 + cb) + leaky(sagg@sw + sb)  -> buf3
    gemm_mfma<3, false><<<nb_g, 256, 0, stream>>>(
        buf0, wt_cw01, H, buf1, wt_cw11, buf2, wt_sw1,
        cheb_b1, sage_b1, buf3, N);
    // xh2 = t1 @ (lin_w1@pre_w2) + merged bias        -> buf0
    gemm_mfma<1, false><<<nb_g, 256, 0, stream>>>(
        buf3, wt_Wm1, H, nullptr, nullptr, nullptr, nullptr,
        bm1, nullptr, buf0, N);

    // ---- cell 2 ----
    aggregate_packed<<<nb_w, 256, 0, stream>>>(buf0, offs, slot_src, slot_nrm,
                                               slot_we, loop_w, cnt, buf1, buf2, N);
    gemm_mfma<3, false><<<nb_g, 256, 0, stream>>>(
        buf0, wt_cw02, H, buf1, wt_cw12, buf2, wt_sw2,
        cheb_b2, sage_b2, buf3, N);

    // classifier with merged lin2+cls weights + log_softmax -> d_out
    cls_kernel<<<nb_w, 256, 0, stream>>>(buf3, Wm2, bm2, (float*)d_out, N, C);
}

// Round 6
// 632.408 us; speedup vs baseline: 1.7849x; 1.2843x over previous
//
#include <hip/hip_runtime.h>
#include <hip/hip_bf16.h>
#include <math.h>

// ---------------------------------------------------------------------------
// NasAutoGraphC round 6.
// r5 post-mortem: GEMMs off the critical path (all <83us); top dispatch was
// cls_kernel (83us, 40/64 lanes, serial 128-fmaf chain). This round:
//   * cls_mfma: classifier on MFMA (split-bf16, merged lin2+cls weights
//     padded to 48 cols) with log_softmax fused in-register via 16-lane
//     __shfl_xor reductions over the C/D fragment layout.
//   * 3-phase scan replaces the single-block scan (was 1 CU, 40 serial
//     chunks x 3 barriers).
//   * aggregate: 2-edge manual unroll for gather ILP.
// Carried from r5: packed hi/lo bf16 activations, 3x mfma_16x16x32_bf16
// split product, merged weights (lin1@pre2, lin2@cls), no-LDS MFMA GEMMs.
// ---------------------------------------------------------------------------

typedef __attribute__((ext_vector_type(8))) short bf16x8;
typedef __attribute__((ext_vector_type(4))) float f32x4;

__device__ __forceinline__ float leaky01(float v) {
    return v > 0.f ? v : 0.01f * v;
}

// ---- packed hi/lo bf16 helpers ---------------------------------------------

__device__ __forceinline__ uint32_t rne_bf16(float f) {
    uint32_t u = __float_as_uint(f);
    return (u + 0x7FFFu + ((u >> 16) & 1u)) >> 16;
}
__device__ __forceinline__ uint32_t pack_hilo(float v) {
    uint32_t h = rne_bf16(v);
    float hf = __uint_as_float(h << 16);
    uint32_t l = rne_bf16(v - hf);
    return (h << 16) | l;
}
__device__ __forceinline__ float unpack_hilo(uint32_t p) {
    return __uint_as_float(p & 0xFFFF0000u) + __uint_as_float(p << 16);
}

struct FragPair { bf16x8 hi, lo; };

__device__ __forceinline__ FragPair load_packed_frag(const uint32_t* p) {
    uint4 a = *(const uint4*)p;
    uint4 b = *(const uint4*)(p + 4);
    uint32_t q[8] = {a.x, a.y, a.z, a.w, b.x, b.y, b.z, b.w};
    union { uint32_t u[4]; bf16x8 v; } h, lo;
    #pragma unroll
    for (int i = 0; i < 4; ++i) {
        h.u[i]  = (q[2*i] >> 16)      | (q[2*i+1] & 0xFFFF0000u);
        lo.u[i] = (q[2*i] & 0xFFFFu)  | (q[2*i+1] << 16);
    }
    FragPair r; r.hi = h.v; r.lo = lo.v; return r;
}

__device__ __forceinline__ FragPair cvt_frag_f32(const float* p) {
    float4 a = *(const float4*)p;
    float4 b = *(const float4*)(p + 4);
    float f[8] = {a.x, a.y, a.z, a.w, b.x, b.y, b.z, b.w};
    uint32_t hb[8], lb[8];
    #pragma unroll
    for (int i = 0; i < 8; ++i) {
        hb[i] = rne_bf16(f[i]);
        lb[i] = rne_bf16(f[i] - __uint_as_float(hb[i] << 16));
    }
    union { uint32_t u[4]; bf16x8 v; } h, lo;
    #pragma unroll
    for (int i = 0; i < 4; ++i) {
        h.u[i]  = hb[2*i] | (hb[2*i+1] << 16);
        lo.u[i] = lb[2*i] | (lb[2*i+1] << 16);
    }
    FragPair r; r.hi = h.v; r.lo = lo.v; return r;
}

// ---- graph preprocessing ---------------------------------------------------

__global__ void init_nodes(float* __restrict__ deg, int* __restrict__ cnt,
                           float* __restrict__ loop_w, int n) {
    int i = blockIdx.x * blockDim.x + threadIdx.x;
    if (i < n) { deg[i] = 0.f; cnt[i] = 0; loop_w[i] = 1.0f; }
}

__global__ void edge_pass1(const int* __restrict__ src, const int* __restrict__ dst,
                           const float* __restrict__ ew, float* __restrict__ deg,
                           int* __restrict__ cnt, float* __restrict__ loop_w, int E) {
    int e = blockIdx.x * blockDim.x + threadIdx.x;
    if (e >= E) return;
    int s = src[e], d = dst[e];
    float w = ew[e];
    if (s == d) {
        loop_w[s] = w;                      // PyG keeps existing loop weight
    } else {
        atomicAdd(&deg[s], w);
        atomicAdd(&cnt[d], 1);
    }
}

// ---- 3-phase scan: per-block partial scan -> top scan -> add base ----------

__global__ __launch_bounds__(1024) void scan_blocks(
    const int* __restrict__ cnt, const float* __restrict__ deg,
    int* __restrict__ partial, int* __restrict__ bsum,
    float* __restrict__ dis, int n)
{
    __shared__ int wsum[16];
    const int tid  = threadIdx.x;
    const int lane = tid & 63;
    const int wv   = tid >> 6;
    const int i    = (blockIdx.x << 10) + tid;
    int v = (i < n) ? cnt[i] : 0;
    if (i < n) {
        float d = deg[i];
        dis[i] = (d > 0.f) ? (1.0f / sqrtf(d)) : 0.f;
    }
    int incl = v;
    #pragma unroll
    for (int off = 1; off < 64; off <<= 1) {
        int t = __shfl_up(incl, off);
        if (lane >= off) incl += t;
    }
    if (lane == 63) wsum[wv] = incl;
    __syncthreads();
    if (tid < 16) {
        int s = wsum[tid];
        #pragma unroll
        for (int off = 1; off < 16; off <<= 1) {
            int u = __shfl_up(s, off);
            if (tid >= off) s += u;
        }
        wsum[tid] = s;
    }
    __syncthreads();
    int excl = (wv ? wsum[wv - 1] : 0) + incl - v;
    if (i < n) partial[i] = excl;
    if (tid == 0) bsum[blockIdx.x] = wsum[15];
}

// nb <= 64 required (N=40000 -> nb=40)
__global__ void scan_tops(const int* __restrict__ bsum, int* __restrict__ bbase,
                          int* __restrict__ offsets, int nb, int n) {
    const int tid = threadIdx.x;                 // 64 threads
    int v = (tid < nb) ? bsum[tid] : 0;
    int incl = v;
    #pragma unroll
    for (int off = 1; off < 64; off <<= 1) {
        int t = __shfl_up(incl, off);
        if (tid >= off) incl += t;
    }
    if (tid < nb) bbase[tid] = incl - v;
    if (tid == 63) offsets[n] = incl;            // grand total
}

__global__ void scan_add(int* __restrict__ offsets, int* __restrict__ cursor,
                         const int* __restrict__ bbase, int n) {
    int i = blockIdx.x * blockDim.x + threadIdx.x;
    if (i >= n) return;
    int v = offsets[i] + bbase[i >> 10];
    offsets[i] = v;
    cursor[i]  = v;
}

__global__ void edge_pass2(const int* __restrict__ src, const int* __restrict__ dst,
                           const float* __restrict__ ew, const float* __restrict__ dis,
                           int* __restrict__ cursor, int* __restrict__ slot_src,
                           float* __restrict__ slot_norm, float* __restrict__ slot_we,
                           int E) {
    int e = blockIdx.x * blockDim.x + threadIdx.x;
    if (e >= E) return;
    int s = src[e], d = dst[e];
    if (s == d) return;
    float w = ew[e];
    float nrm = -dis[s] * w * dis[d];
    int pos = atomicAdd(&cursor[d], 1);
    slot_src[pos]  = s;
    slot_norm[pos] = nrm;
    slot_we[pos]   = w;
}

// ---- weight merge (fp32, tiny) ---------------------------------------------

__global__ void merge_weights(const float* __restrict__ A, const float* __restrict__ B,
                              const float* __restrict__ ba, const float* __restrict__ bb,
                              float* __restrict__ Wm, float* __restrict__ bm,
                              int KA, int NB) {
    int idx = blockIdx.x * blockDim.x + threadIdx.x;
    int total = (KA + 1) * NB;
    if (idx >= total) return;
    int r = idx / NB, j = idx - r * NB;
    const float* arow = (r < KA) ? &A[(size_t)r * KA] : ba;
    float acc = 0.f;
    for (int q = 0; q < KA; ++q)
        acc = fmaf(arow[q], B[(size_t)q * NB + j], acc);
    if (r < KA) Wm[(size_t)r * NB + j] = acc;
    else        bm[j] = acc + bb[j];
}

// ---- weight convert: fp32 [K][128] -> packed TRANSPOSED [col][K] -----------
// segs: pre_w1 (K=512, 128 cols) + 7x (K=128, 128 cols) + cls (K=128, 48
// cols, src stride 40, zero-pad cols >= 40).

#define WT_TOTAL (65536 + 7 * 16384 + 48 * 128)

__global__ void convert_weights(const float* s0, const float* s1, const float* s2,
                                const float* s3, const float* s4, const float* s5,
                                const float* s6, const float* s7, const float* s8,
                                uint32_t* __restrict__ dst) {
    int idx = blockIdx.x * blockDim.x + threadIdx.x;
    if (idx >= WT_TOTAL) return;
    if (idx >= 65536 + 7 * 16384) {              // cls segment: [48][128]
        int local = idx - (65536 + 7 * 16384);
        int col = local >> 7, k = local & 127;
        float v = (col < 40) ? s8[(size_t)k * 40 + col] : 0.f;
        dst[idx] = pack_hilo(v);
        return;
    }
    const float* src; int K, local; uint32_t* d;
    if (idx < 65536) { src = s0; K = 512; local = idx; d = dst; }
    else {
        int t = idx - 65536;
        int seg = t >> 14; local = t & 16383; K = 128;
        d = dst + 65536 + (seg << 14);
        src = seg == 0 ? s1 : seg == 1 ? s2 : seg == 2 ? s3 :
              seg == 3 ? s4 : seg == 4 ? s5 : seg == 5 ? s6 : s7;
    }
    int col = local / K, k = local - col * K;
    d[local] = pack_hilo(src[(size_t)k * 128 + col]);
}

// ---- aggregation (packed IO): wave per node, 2-edge unrolled ---------------

__global__ __launch_bounds__(256) void aggregate_packed(
    const uint32_t* __restrict__ xh, const int* __restrict__ offsets,
    const int* __restrict__ slot_src, const float* __restrict__ slot_norm,
    const float* __restrict__ slot_we, const float* __restrict__ loop_w,
    const int* __restrict__ cnt, uint32_t* __restrict__ tx1,
    uint32_t* __restrict__ sagg, int n)
{
    const int lane = threadIdx.x & 63;
    const int wv   = threadIdx.x >> 6;
    const int node = (blockIdx.x << 2) + wv;
    if (node >= n) return;
    const int beg = offsets[node], end = offsets[node + 1];
    const int c = lane << 1;
    float ax = 0.f, ay = 0.f, sx = 0.f, sy = 0.f;
    float ax2 = 0.f, ay2 = 0.f, sx2 = 0.f, sy2 = 0.f;
    int e = beg;
    for (; e + 1 < end; e += 2) {
        const int   s0 = slot_src[e],     s1 = slot_src[e + 1];
        const float n0 = slot_norm[e],    n1 = slot_norm[e + 1];
        const float w0 = slot_we[e],      w1 = slot_we[e + 1];
        const uint2 p0 = *(const uint2*)&xh[((size_t)s0 << 7) + c];
        const uint2 p1 = *(const uint2*)&xh[((size_t)s1 << 7) + c];
        const float v0x = unpack_hilo(p0.x), v0y = unpack_hilo(p0.y);
        const float v1x = unpack_hilo(p1.x), v1y = unpack_hilo(p1.y);
        ax  = fmaf(n0, v0x, ax);  ay  = fmaf(n0, v0y, ay);
        sx  = fmaf(w0, v0x, sx);  sy  = fmaf(w0, v0y, sy);
        ax2 = fmaf(n1, v1x, ax2); ay2 = fmaf(n1, v1y, ay2);
        sx2 = fmaf(w1, v1x, sx2); sy2 = fmaf(w1, v1y, sy2);
    }
    if (e < end) {
        const int   s0 = slot_src[e];
        const float n0 = slot_norm[e];
        const float w0 = slot_we[e];
        const uint2 p0 = *(const uint2*)&xh[((size_t)s0 << 7) + c];
        const float v0x = unpack_hilo(p0.x), v0y = unpack_hilo(p0.y);
        ax = fmaf(n0, v0x, ax); ay = fmaf(n0, v0y, ay);
        sx = fmaf(w0, v0x, sx); sy = fmaf(w0, v0y, sy);
    }
    ax += ax2; ay += ay2; sx += sx2; sy += sy2;
    const uint2 ps = *(const uint2*)&xh[((size_t)node << 7) + c];
    const float lw = loop_w[node];
    sx = fmaf(lw, unpack_hilo(ps.x), sx); sy = fmaf(lw, unpack_hilo(ps.y), sy);
    const float inv = 1.0f / (float)(cnt[node] + 1);
    *(uint2*)&tx1[((size_t)node << 7) + c]  =
        make_uint2(pack_hilo(ax), pack_hilo(ay));
    *(uint2*)&sagg[((size_t)node << 7) + c] =
        make_uint2(pack_hilo(sx * inv), pack_hilo(sy * inv));
}

// ---- split-bf16 MFMA GEMM (no LDS, no barriers) ----------------------------

template<bool F32>
__device__ __forceinline__ void gemm_part(
    const void* Av, const uint32_t* __restrict__ Wt, int K,
    int rbase, int cbase, int l15, int kg, f32x4 acc[2][4])
{
    for (int k = 0; k < K; k += 32) {
        FragPair Af[2];
        #pragma unroll
        for (int m = 0; m < 2; ++m) {
            const int row = rbase + m * 16 + l15;
            if constexpr (F32)
                Af[m] = cvt_frag_f32((const float*)Av + (size_t)row * K + k + kg * 8);
            else
                Af[m] = load_packed_frag((const uint32_t*)Av + (size_t)row * K + k + kg * 8);
        }
        #pragma unroll
        for (int n = 0; n < 4; ++n) {
            const FragPair Bf =
                load_packed_frag(Wt + (size_t)(cbase + n * 16 + l15) * K + k + kg * 8);
            #pragma unroll
            for (int m = 0; m < 2; ++m) {
                acc[m][n] = __builtin_amdgcn_mfma_f32_16x16x32_bf16(Af[m].hi, Bf.hi, acc[m][n], 0, 0, 0);
                acc[m][n] = __builtin_amdgcn_mfma_f32_16x16x32_bf16(Af[m].hi, Bf.lo, acc[m][n], 0, 0, 0);
                acc[m][n] = __builtin_amdgcn_mfma_f32_16x16x32_bf16(Af[m].lo, Bf.hi, acc[m][n], 0, 0, 0);
            }
        }
    }
}

template<int NPARTS, bool AF32>
__global__ __launch_bounds__(256, 3) void gemm_mfma(
    const void* __restrict__ A1, const uint32_t* __restrict__ Wt1, int K1,
    const uint32_t* __restrict__ A2, const uint32_t* __restrict__ Wt2,
    const uint32_t* __restrict__ A3, const uint32_t* __restrict__ Wt3,
    const float* __restrict__ b1, const float* __restrict__ b2,
    uint32_t* __restrict__ out, int M)
{
    const int tid  = threadIdx.x;
    const int lane = tid & 63;
    const int w    = tid >> 6;
    const int mw   = w >> 1, nw = w & 1;
    const int l15  = lane & 15;
    const int kg   = lane >> 4;
    const int rbase = blockIdx.x * 64 + mw * 32;
    const int cbase = nw * 64;

    f32x4 accA[2][4];
    #pragma unroll
    for (int m = 0; m < 2; ++m)
        #pragma unroll
        for (int n = 0; n < 4; ++n) accA[m][n] = (f32x4)0.f;

    gemm_part<AF32>(A1, Wt1, K1, rbase, cbase, l15, kg, accA);

    if constexpr (NPARTS == 3) {
        gemm_part<false>(A2, Wt2, 128, rbase, cbase, l15, kg, accA);
        f32x4 accB[2][4];
        #pragma unroll
        for (int m = 0; m < 2; ++m)
            #pragma unroll
            for (int n = 0; n < 4; ++n) accB[m][n] = (f32x4)0.f;
        gemm_part<false>(A3, Wt3, 128, rbase, cbase, l15, kg, accB);

        #pragma unroll
        for (int n = 0; n < 4; ++n) {
            const int col = cbase + n * 16 + l15;
            const float bb1 = b1[col], bb2 = b2[col];
            #pragma unroll
            for (int m = 0; m < 2; ++m)
                #pragma unroll
                for (int r = 0; r < 4; ++r) {
                    const int row = rbase + m * 16 + kg * 4 + r;
                    float v = leaky01(accA[m][n][r] + bb1) + leaky01(accB[m][n][r] + bb2);
                    out[(size_t)row * 128 + col] = pack_hilo(v);
                }
        }
    } else {
        #pragma unroll
        for (int n = 0; n < 4; ++n) {
            const int col = cbase + n * 16 + l15;
            const float bb1 = b1[col];
            #pragma unroll
            for (int m = 0; m < 2; ++m)
                #pragma unroll
                for (int r = 0; r < 4; ++r) {
                    const int row = rbase + m * 16 + kg * 4 + r;
                    out[(size_t)row * 128 + col] = pack_hilo(accA[m][n][r] + bb1);
                }
        }
    }
    (void)M;
}

// ---- classifier: split-bf16 MFMA + fused log_softmax -----------------------
// Wt padded to 48 cols (cols 40..47 zero). Block = 4 waves x 32 rows = 128
// rows. C/D layout col=n*16+l15, row=kg*4+r: a full logit row lives in one
// 16-lane group -> shfl_xor{1,2,4,8} row reductions, no LDS.

__global__ __launch_bounds__(256) void cls_mfma(
    const uint32_t* __restrict__ x2, const uint32_t* __restrict__ Wt,
    const float* __restrict__ bias, float* __restrict__ out, int M)
{
    const int tid  = threadIdx.x;
    const int lane = tid & 63;
    const int w    = tid >> 6;
    const int l15  = lane & 15;
    const int kg   = lane >> 4;
    const int rbase = blockIdx.x * 128 + w * 32;

    f32x4 acc[2][3];
    #pragma unroll
    for (int m = 0; m < 2; ++m)
        #pragma unroll
        for (int n = 0; n < 3; ++n) acc[m][n] = (f32x4)0.f;

    #pragma unroll
    for (int k = 0; k < 128; k += 32) {
        FragPair Af[2];
        #pragma unroll
        for (int m = 0; m < 2; ++m) {
            int row = rbase + m * 16 + l15;
            if (row > M - 1) row = M - 1;
            Af[m] = load_packed_frag(x2 + (size_t)row * 128 + k + kg * 8);
        }
        #pragma unroll
        for (int n = 0; n < 3; ++n) {
            const FragPair Bf =
                load_packed_frag(Wt + (size_t)(n * 16 + l15) * 128 + k + kg * 8);
            #pragma unroll
            for (int m = 0; m < 2; ++m) {
                acc[m][n] = __builtin_amdgcn_mfma_f32_16x16x32_bf16(Af[m].hi, Bf.hi, acc[m][n], 0, 0, 0);
                acc[m][n] = __builtin_amdgcn_mfma_f32_16x16x32_bf16(Af[m].hi, Bf.lo, acc[m][n], 0, 0, 0);
                acc[m][n] = __builtin_amdgcn_mfma_f32_16x16x32_bf16(Af[m].lo, Bf.hi, acc[m][n], 0, 0, 0);
            }
        }
    }

    const bool v2 = (l15 < 8);                   // col 32+l15 < 40
    const float bv0 = bias[l15];
    const float bv1 = bias[16 + l15];
    const float bv2 = v2 ? bias[32 + l15] : 0.f;

    #pragma unroll
    for (int m = 0; m < 2; ++m)
        #pragma unroll
        for (int r = 0; r < 4; ++r) {
            const int row = rbase + m * 16 + kg * 4 + r;
            float x0 = acc[m][0][r] + bv0;
            float x1 = acc[m][1][r] + bv1;
            float x2v = v2 ? (acc[m][2][r] + bv2) : -INFINITY;
            float mx = fmaxf(fmaxf(x0, x1), x2v);
            #pragma unroll
            for (int off = 1; off < 16; off <<= 1)
                mx = fmaxf(mx, __shfl_xor(mx, off));
            float s = __expf(x0 - mx) + __expf(x1 - mx) + (v2 ? __expf(x2v - mx) : 0.f);
            #pragma unroll
            for (int off = 1; off < 16; off <<= 1)
                s += __shfl_xor(s, off);
            const float ls = logf(s);
            if (row < M) {
                float* op = &out[(size_t)row * 40];
                op[l15]      = x0 - mx - ls;
                op[16 + l15] = x1 - mx - ls;
                if (v2) op[32 + l15] = x2v - mx - ls;
            }
        }
}

// ---------------------------------------------------------------------------

extern "C" void kernel_launch(void* const* d_in, const int* in_sizes, int n_in,
                              void* d_out, int out_size, void* d_ws, size_t ws_size,
                              hipStream_t stream)
{
    const float* x        = (const float*)d_in[0];
    const int*   ei       = (const int*)d_in[1];
    const float* ew       = (const float*)d_in[2];
    const float* pre_w1   = (const float*)d_in[3];
    const float* pre_b1   = (const float*)d_in[4];
    const float* cheb_w01 = (const float*)d_in[5];
    const float* cheb_w11 = (const float*)d_in[6];
    const float* cheb_b1  = (const float*)d_in[7];
    const float* sage_w1  = (const float*)d_in[8];
    const float* sage_b1  = (const float*)d_in[9];
    const float* lin_w1   = (const float*)d_in[10];
    const float* lin_b1   = (const float*)d_in[11];
    const float* pre_w2   = (const float*)d_in[12];
    const float* pre_b2   = (const float*)d_in[13];
    const float* cheb_w02 = (const float*)d_in[14];
    const float* cheb_w12 = (const float*)d_in[15];
    const float* cheb_b2  = (const float*)d_in[16];
    const float* sage_w2  = (const float*)d_in[17];
    const float* sage_b2  = (const float*)d_in[18];
    const float* lin_w2   = (const float*)d_in[19];
    const float* lin_b2   = (const float*)d_in[20];
    const float* cls_w    = (const float*)d_in[21];
    const float* cls_b    = (const float*)d_in[22];

    const int H    = 128;
    const int F_IN = in_sizes[3] / H;       // 512
    const int N    = in_sizes[0] / F_IN;    // 40000
    const int E    = in_sizes[2];           // 640000
    const int* src = ei;
    const int* dst = ei + E;

    // workspace carve-up (256B aligned)
    char* p = (char*)d_ws;
    auto alloc = [&](size_t bytes) -> void* {
        void* r = (void*)p;
        p += (bytes + 255) & ~(size_t)255;
        return r;
    };
    uint32_t* buf0 = (uint32_t*)alloc((size_t)N * 128 * 4);   // packed activations
    uint32_t* buf1 = (uint32_t*)alloc((size_t)N * 128 * 4);
    uint32_t* buf2 = (uint32_t*)alloc((size_t)N * 128 * 4);
    uint32_t* buf3 = (uint32_t*)alloc((size_t)N * 128 * 4);
    float* deg     = (float*)alloc((size_t)N * 4);
    float* dis     = (float*)alloc((size_t)N * 4);
    float* loop_w  = (float*)alloc((size_t)N * 4);
    int*   cnt     = (int*)alloc((size_t)N * 4);
    int*   offs    = (int*)alloc((size_t)(N + 1) * 4);
    int*   cursor  = (int*)alloc((size_t)N * 4);
    int*   bsum    = (int*)alloc(64 * 4);
    int*   bbase   = (int*)alloc(64 * 4);
    int*   slot_src  = (int*)alloc((size_t)E * 4);
    float* slot_nrm  = (float*)alloc((size_t)E * 4);
    float* slot_we   = (float*)alloc((size_t)E * 4);
    float* Wm1 = (float*)alloc((size_t)H * H * 4);    // lin_w1 @ pre_w2 (fp32)
    float* bm1 = (float*)alloc((size_t)H * 4);
    float* Wm2 = (float*)alloc((size_t)H * 40 * 4);   // lin_w2 @ cls_w (fp32)
    float* bm2 = (float*)alloc((size_t)40 * 4);
    uint32_t* wt = (uint32_t*)alloc((size_t)WT_TOTAL * 4);    // packed W^T
    (void)ws_size; (void)n_in; (void)out_size;

    uint32_t* wt_pre  = wt;                 // [128][512]
    uint32_t* wt_cw01 = wt + 65536;
    uint32_t* wt_cw11 = wt_cw01 + 16384;
    uint32_t* wt_sw1  = wt_cw11 + 16384;
    uint32_t* wt_Wm1  = wt_sw1  + 16384;
    uint32_t* wt_cw02 = wt_Wm1  + 16384;
    uint32_t* wt_cw12 = wt_cw02 + 16384;
    uint32_t* wt_sw2  = wt_cw12 + 16384;
    uint32_t* wt_cls  = wt_sw2  + 16384;    // [48][128]

    const int nb_n = (N + 255) / 256;
    const int nb_e = (E + 255) / 256;
    const int nb_w = (N + 3) / 4;           // wave-per-node kernels
    const int nb_g = (N + 63) / 64;         // MFMA GEMM blocks (625)
    const int nb_s = (N + 1023) / 1024;     // scan blocks (40)
    const int nb_c = (N + 127) / 128;       // cls blocks (313)

    // graph preprocessing + weight merge/convert
    init_nodes<<<nb_n, 256, 0, stream>>>(deg, cnt, loop_w, N);
    edge_pass1<<<nb_e, 256, 0, stream>>>(src, dst, ew, deg, cnt, loop_w, E);
    scan_blocks<<<nb_s, 1024, 0, stream>>>(cnt, deg, offs, bsum, dis, N);
    scan_tops<<<1, 64, 0, stream>>>(bsum, bbase, offs, nb_s, N);
    scan_add<<<nb_n, 256, 0, stream>>>(offs, cursor, bbase, N);
    edge_pass2<<<nb_e, 256, 0, stream>>>(src, dst, ew, dis, cursor,
                                         slot_src, slot_nrm, slot_we, E);
    merge_weights<<<((H + 1) * H + 255) / 256, 256, 0, stream>>>(
        lin_w1, pre_w2, lin_b1, pre_b2, Wm1, bm1, H, H);
    merge_weights<<<((H + 1) * 40 + 255) / 256, 256, 0, stream>>>(
        lin_w2, cls_w, lin_b2, cls_b, Wm2, bm2, H, 40);
    convert_weights<<<(WT_TOTAL + 255) / 256, 256, 0, stream>>>(
        pre_w1, cheb_w01, cheb_w11, sage_w1, Wm1, cheb_w02, cheb_w12, sage_w2,
        Wm2, wt);

    // ---- cell 1 ----
    gemm_mfma<1, true><<<nb_g, 256, 0, stream>>>(
        x, wt_pre, F_IN, nullptr, nullptr, nullptr, nullptr,
        pre_b1, nullptr, buf0, N);
    aggregate_packed<<<nb_w, 256, 0, stream>>>(buf0, offs, slot_src, slot_nrm,
                                               slot_we, loop_w, cnt, buf1, buf2, N);
    gemm_mfma<3, false><<<nb_g, 256, 0, stream>>>(
        buf0, wt_cw01, H, buf1, wt_cw11, buf2, wt_sw1,
        cheb_b1, sage_b1, buf3, N);
    gemm_mfma<1, false><<<nb_g, 256, 0, stream>>>(
        buf3, wt_Wm1, H, nullptr, nullptr, nullptr, nullptr,
        bm1, nullptr, buf0, N);

    // ---- cell 2 ----
    aggregate_packed<<<nb_w, 256, 0, stream>>>(buf0, offs, slot_src, slot_nrm,
                                               slot_we, loop_w, cnt, buf1, buf2, N);
    gemm_mfma<3, false><<<nb_g, 256, 0, stream>>>(
        buf0, wt_cw02, H, buf1, wt_cw12, buf2, wt_sw2,
        cheb_b2, sage_b2, buf3, N);

    // classifier (merged lin2+cls, MFMA) + fused log_softmax -> d_out
    cls_mfma<<<nb_c, 256, 0, stream>>>(buf3, wt_cls, bm2, (float*)d_out, N);
}